// Round 1
// baseline (121.686 us; speedup 1.0000x reference)
//
#include <hip/hip_runtime.h>
#include <math.h>

#define NQ 10
#define NSTATE 1024
#define NPAR 100
#define FDIM 256
#define BATCH 256
#define NOUT 30
#define TWO_PI_F 6.283185307179586f

__device__ __forceinline__ float2 cmul(float2 a, float2 b) {
    return make_float2(fmaf(a.x, b.x, -a.y*b.y), fmaf(a.x, b.y, a.y*b.x));
}
__device__ __forceinline__ float2 cadd(float2 a, float2 b) {
    return make_float2(a.x + b.x, a.y + b.y);
}

// CRX: controlled RX(theta). bc/bt are BIT positions (bit = 9 - wire).
// RX = [[c, -i s], [-i s, c]], applied on the control==1 subspace.
__device__ __forceinline__ void crx_gate(float2* st, float2 cshalf, int bc, int bt, int tid) {
    const float c = cshalf.x, s = cshalf.y;
    const int b_lo = bc < bt ? bc : bt;
    const int b_hi = bc < bt ? bt : bc;
    int i = tid;                                  // 256 pairs, one per thread
    i = ((i >> b_lo) << (b_lo + 1)) | (i & ((1 << b_lo) - 1));
    i = ((i >> b_hi) << (b_hi + 1)) | (i & ((1 << b_hi) - 1));
    const int i0 = i | (1 << bc);                 // control = 1, target = 0
    const int i1 = i0 | (1 << bt);
    float2 a0 = st[i0], a1 = st[i1];
    // new0 = c*a0 - i*s*a1 ; new1 = c*a1 - i*s*a0
    st[i0] = make_float2(fmaf(c, a0.x,  s * a1.y), fmaf(c, a0.y, -s * a1.x));
    st[i1] = make_float2(fmaf(c, a1.x,  s * a0.y), fmaf(c, a1.y, -s * a0.x));
    __syncthreads();
}

__global__ __launch_bounds__(256) void qsb_branch(
    const float* __restrict__ x,
    const float* __restrict__ W1, const float* __restrict__ b1, const float* __restrict__ base1,
    const float* __restrict__ W2, const float* __restrict__ b2, const float* __restrict__ base2,
    const float* __restrict__ W3, const float* __restrict__ b3, const float* __restrict__ base3,
    float* __restrict__ m_ws)
{
    const int b   = blockIdx.x;   // batch item
    const int br  = blockIdx.y;   // branch 0..2
    const int tid = threadIdx.x;

    const float* W    = (br == 0) ? W1    : (br == 1) ? W2    : W3;
    const float* bias = (br == 0) ? b1    : (br == 1) ? b2    : b3;
    const float* base = (br == 0) ? base1 : (br == 1) ? base2 : base3;
    float* m_out = m_ws + (size_t)br * (BATCH * NOUT);

    __shared__ float  xrow[FDIM];
    __shared__ float2 cs[NPAR];      // (cos(theta/2), sin(theta/2)) per param
    __shared__ float2 st[NSTATE];    // statevector
    __shared__ float  redA[4], redB[4], redC[4];

    // stage x row
    xrow[tid] = x[(size_t)b * FDIM + tid];
    __syncthreads();

    // params: p = sigmoid(x.W^T + bias + base) * 2pi ; store half-angle trig
    if (tid < NPAR) {
        const float* wr = W + (size_t)tid * FDIM;
        float acc = 0.f;
        #pragma unroll 8
        for (int k = 0; k < FDIM; ++k) acc = fmaf(xrow[k], wr[k], acc);
        acc += bias[tid] + base[tid];
        float p = TWO_PI_F / (1.f + expf(-acc));
        float sh, ch;
        __sincosf(0.5f * p, &sh, &ch);
        cs[tid] = make_float2(ch, sh);
    }
    // init |00..0>
    for (int i = tid; i < NSTATE; i += 256)
        st[i] = make_float2(i == 0 ? 1.f : 0.f, 0.f);
    __syncthreads();

    int idx = 0;
    for (int layer = 0; layer < 2; ++layer) {
        // fused RZ*RY*RX per qubit (applied RX first)
        for (int q = 0; q < NQ; ++q) {
            const float2 X = cs[idx], Y = cs[idx + 1], Z = cs[idx + 2];
            idx += 3;
            const float cx = X.x, sx = X.y, cy = Y.x, sy = Y.y, cz = Z.x, sz = Z.y;
            // M = Ry*Rx:
            const float2 m00 = make_float2( cy * cx,  sy * sx);
            const float2 m01 = make_float2(-sy * cx, -cy * sx);
            const float2 m10 = make_float2( sy * cx, -cy * sx);
            const float2 m11 = make_float2( cy * cx, -sy * sx);
            // U = Rz*M: row0 *= (cz - i sz), row1 *= (cz + i sz)
            const float2 z0 = make_float2(cz, -sz), z1 = make_float2(cz, sz);
            const float2 u00 = cmul(z0, m00), u01 = cmul(z0, m01);
            const float2 u10 = cmul(z1, m10), u11 = cmul(z1, m11);

            const int bpos = 9 - q;
            const int bit  = 1 << bpos;
            #pragma unroll
            for (int pp = 0; pp < 2; ++pp) {
                const int p   = tid + pp * 256;       // 512 pairs
                const int low = p & (bit - 1);
                const int i0  = ((p ^ low) << 1) | low;
                const int i1  = i0 | bit;
                float2 a0 = st[i0], a1 = st[i1];
                float2 n0 = cadd(cmul(u00, a0), cmul(u01, a1));
                float2 n1 = cadd(cmul(u10, a0), cmul(u11, a1));
                st[i0] = n0; st[i1] = n1;
            }
            __syncthreads();
        }
        // ring CRX forward: control q, target (q+1)%10
        for (int q = 0; q < NQ; ++q) {
            crx_gate(st, cs[idx], 9 - q, 9 - ((q + 1) % NQ), tid);
            idx++;
        }
        // ring CRX backward: q = 9..0, control q, target (q-1)%10
        for (int q = NQ - 1; q >= 0; --q) {
            crx_gate(st, cs[idx], 9 - q, 9 - ((q + NQ - 1) % NQ), tid);
            idx++;
        }
    }

    // measurements: X_w = 2 Re z01, Y_w = 2 Im z01, Z_w = p0 - p1
    const int wv = tid >> 6, lane = tid & 63;
    for (int w = 0; w < NQ; ++w) {
        const int bpos = 9 - w;
        const int bit  = 1 << bpos;
        float sre = 0.f, sim = 0.f, szz = 0.f;
        #pragma unroll
        for (int pp = 0; pp < 2; ++pp) {
            const int p   = tid + pp * 256;
            const int low = p & (bit - 1);
            const int i0  = ((p ^ low) << 1) | low;
            const int i1  = i0 | bit;
            float2 a0 = st[i0], a1 = st[i1];
            sre += a0.x * a1.x + a0.y * a1.y;     // Re(conj(a0)*a1)
            sim += a0.x * a1.y - a0.y * a1.x;     // Im(conj(a0)*a1)
            szz += (a0.x * a0.x + a0.y * a0.y) - (a1.x * a1.x + a1.y * a1.y);
        }
        #pragma unroll
        for (int off = 32; off > 0; off >>= 1) {
            sre += __shfl_down(sre, off, 64);
            sim += __shfl_down(sim, off, 64);
            szz += __shfl_down(szz, off, 64);
        }
        if (lane == 0) { redA[wv] = sre; redB[wv] = sim; redC[wv] = szz; }
        __syncthreads();
        if (tid == 0) {
            const float Xv = 2.f * (redA[0] + redA[1] + redA[2] + redA[3]);
            const float Yv = 2.f * (redB[0] + redB[1] + redB[2] + redB[3]);
            const float Zv = redC[0] + redC[1] + redC[2] + redC[3];
            m_out[(size_t)b * NOUT + w]      = Xv;
            m_out[(size_t)b * NOUT + 10 + w] = Yv;
            m_out[(size_t)b * NOUT + 20 + w] = Zv;
        }
        __syncthreads();
    }
}

__global__ __launch_bounds__(256) void qsb_combine(
    const float* __restrict__ m,
    const float* __restrict__ ar_, const float* __restrict__ ai_,
    const float* __restrict__ br_, const float* __restrict__ bi_,
    const float* __restrict__ gr_, const float* __restrict__ gi_,
    float* __restrict__ out)
{
    const int i = blockIdx.x * blockDim.x + threadIdx.x;
    if (i >= BATCH * NOUT) return;
    const float ar = ar_[0], ai = ai_[0];
    const float br = br_[0], bi = bi_[0];
    const float gr = gr_[0], gi = gi_[0];
    const float inv = 1.f / sqrtf(ar*ar + ai*ai + br*br + bi*bi + gr*gr + gi*gi + 1e-9f);
    const float m1 = m[i];
    const float m2 = m[BATCH * NOUT + i];
    const float m3 = m[2 * BATCH * NOUT + i];
    const float re = (ar * m1 + br * m2 + gr * m3) * inv;
    const float im = (ai * m1 + bi * m2 + gi * m3) * inv;
    out[i] = sqrtf(re * re + im * im);
}

extern "C" void kernel_launch(void* const* d_in, const int* in_sizes, int n_in,
                              void* d_out, int out_size, void* d_ws, size_t ws_size,
                              hipStream_t stream)
{
    (void)in_sizes; (void)n_in; (void)out_size; (void)ws_size;
    const float* x     = (const float*)d_in[0];
    const float* W1    = (const float*)d_in[1];
    const float* b1    = (const float*)d_in[2];
    const float* W2    = (const float*)d_in[3];
    const float* b2    = (const float*)d_in[4];
    const float* W3    = (const float*)d_in[5];
    const float* b3    = (const float*)d_in[6];
    const float* base1 = (const float*)d_in[7];
    const float* base2 = (const float*)d_in[8];
    const float* base3 = (const float*)d_in[9];
    const float* ar    = (const float*)d_in[10];
    const float* ai    = (const float*)d_in[11];
    const float* br    = (const float*)d_in[12];
    const float* bi    = (const float*)d_in[13];
    const float* gr    = (const float*)d_in[14];
    const float* gi    = (const float*)d_in[15];

    float* m_ws = (float*)d_ws;          // 3 * 256 * 30 floats = 92160 B
    float* out  = (float*)d_out;

    dim3 grid(BATCH, 3), block(256);
    qsb_branch<<<grid, block, 0, stream>>>(x, W1, b1, base1, W2, b2, base2,
                                           W3, b3, base3, m_ws);
    qsb_combine<<<(BATCH * NOUT + 255) / 256, 256, 0, stream>>>(
        m_ws, ar, ai, br, bi, gr, gi, out);
}